// Round 14
// baseline (187.615 us; speedup 1.0000x reference)
//
#include <hip/hip_runtime.h>

// Problem constants (from reference)
#define BATCH 16384
#define CNUM  8
#define DIN   256
#define NH0   512
#define NH1   256

#define BT       64            // batch rows per block (fallback kernel)
#define BTM      128           // batch rows per block (main kernel)
#define NTMAIN   1024          // 16 waves
#define NTHREADS 512           // fallback

#define X_ELEMS  (BATCH * DIN)        // 4194304
#define W0_ELEMS (CNUM * NH0 * DIN)   // 1048576
#define W1_ELEMS (CNUM * NH1 * NH0)   // 1048576
#define WS_NEED  ((size_t)(X_ELEMS + W0_ELEMS + W1_ELEMS) * 2)  // 12.6 MB bf16

typedef __bf16 bf16x8 __attribute__((ext_vector_type(8)));
typedef __bf16 bf16x4 __attribute__((ext_vector_type(4)));
typedef float  f32x4  __attribute__((ext_vector_type(4)));
typedef float  f32x8  __attribute__((ext_vector_type(8)));
typedef float  f32x16 __attribute__((ext_vector_type(16)));

#define MFMA16(a, b, c) __builtin_amdgcn_mfma_f32_16x16x32_bf16((a), (b), (c), 0, 0, 0)
#define MFMA32(a, b, c) __builtin_amdgcn_mfma_f32_32x32x16_bf16((a), (b), (c), 0, 0, 0)

// ---------------------------------------------------------------------------
// Prep: fp32 -> bf16 for x, W0, W1 into ws.  786432 chunks x 8 elems.
// ---------------------------------------------------------------------------
__global__ __launch_bounds__(256)
void cvt_bf16(const float* __restrict__ x, const float* __restrict__ W0,
              const float* __restrict__ W1, __bf16* __restrict__ ws) {
    const int i = blockIdx.x * 256 + threadIdx.x;   // chunk of 8 elems
    const float* src;
    __bf16* dst;
    int off;
    if (i < X_ELEMS / 8)                 { src = x;  dst = ws;                        off = i * 8; }
    else if (i < (X_ELEMS + W0_ELEMS)/8) { src = W0; dst = ws + X_ELEMS;             off = (i - X_ELEMS/8) * 8; }
    else                                 { src = W1; dst = ws + X_ELEMS + W0_ELEMS;  off = (i - (X_ELEMS + W0_ELEMS)/8) * 8; }
    f32x8 v = *(const f32x8*)(src + off);
    bf16x8 r;
    #pragma unroll
    for (int j = 0; j < 8; ++j) r[j] = (__bf16)v[j];
    *(bf16x8*)(dst + off) = r;
}

// ---------------------------------------------------------------------------
// Main fused kernel: BT=128, 16 waves, 4 barriers/block.
// grid = (BATCH/BTM)*CNUM = 1024; c = blockIdx&7 (XCD round-robin).
//
// r10 (94.4 us best) with L1 switched to 32x32x16 MFMA + m-half split:
//   L0 (r10 EXACT): wave w owns n-slice 32 (at 0..1), m = 128. 2 global
//     A-streams, 8 ds_read + 16 MFMA(16x16x32) per k-step.
//   L1 (NEW): wave (ns = w>>1, mh = w&1) owns o-slice 32, m-half 64.
//     ONE global A-stream (a 32x32 A b128-load covers 32 o-rows), 2 ds_read
//     + 2 MFMA(32x32x16) per k-step, 32 k-steps. L1 LDS reads per block
//     halve (2048 -> 1024); W1 rows read by 2 waves (mh pair) -> +256 KB
//     L2/block (cheap). This isolates r12's confound: m-split WITHOUT a
//     second A-stream.
//
// LDS layouts:
//   xs (L0 B): 64 granules of 16m x 32k (r10 exact; lane l = row l&15,
//     k-slot l>>4 -> lane-contiguous ds_read_b128, conflict-free).
//   h0 (L1 B): 128 granules of 32m x 16k (r5-verified 32-format: value
//     (m,k) at elem ((m&31) + 32*((k>>3)&1))*8 + (k&7); lane l reads
//     m=l&31, k=8*(l>>5)+j at l*16 bytes -> conflict-free).
//     granule g = (m>>5)*32 + (k>>4).
// ---------------------------------------------------------------------------
__global__ __launch_bounds__(NTMAIN, 4)
void confounder_main(const __bf16* __restrict__ ws,
                     const float* __restrict__ b0,
                     const float* __restrict__ b1,
                     const float* __restrict__ W2,
                     const float* __restrict__ b2,
                     float* __restrict__ out) {
    __shared__ __align__(16) __bf16 h0s[BTM * NH0];  // 131072 B
    __shared__ float red[16][64];                    // 4096 B
    __bf16* xs = h0s;                                // granules 0..63 alias (L0)

    const __bf16* xbf = ws;
    const __bf16* w0b = ws + X_ELEMS;
    const __bf16* w1b = ws + X_ELEMS + W0_ELEMS;

    const int c    = blockIdx.x & 7;
    const int mb   = blockIdx.x >> 3;
    const int row0 = mb * BTM;

    const int tid  = threadIdx.x;
    const int w    = tid >> 6;    // wave 0..15
    const int lane = tid & 63;
    const int l15  = lane & 15;
    const int l4   = lane >> 4;   // 0..3
    const int l31  = lane & 31;
    const int l5   = lane >> 5;   // 0..1
    const int ns   = w >> 1;      // 0..7: L1 o-slice
    const int mh   = w & 1;       // 0..1: L1 m half

    // ---- stage x tile (128 m x 256 k) into granules 0..63, frag-major -----
    #pragma unroll
    for (int q = 0; q < 4; ++q) {
        const int p  = w * 4 + q;             // 0..63
        const int mt = p >> 3, kc = p & 7;
        bf16x8 v = *(const bf16x8*)(xbf + (size_t)(row0 + mt * 16 + l15) * DIN + kc * 32 + 8 * l4);
        *(bf16x8*)(xs + (p * 64 + lane) * 8) = v;
    }

    // W0 rows: wave w covers n = w*32 + at*16 + l15 (at 0..1)  [r10 exact]
    const __bf16* w0r = w0b + ((size_t)c * NH0 + w * 32 + l15) * DIN + 8 * l4;
    // W1 rows (32x32 A): o = ns*32 + l31, k-offset 8*l5
    const __bf16* w1r = w1b + ((size_t)c * NH1 + ns * 32 + l31) * NH0 + 8 * l5;

    // prefetch L0 ks=0 fragments across the barrier
    bf16x8 a0 = *(const bf16x8*)(w0r);
    bf16x8 a1 = *(const bf16x8*)(w0r + 16 * DIN);
    __syncthreads();                                   // [barrier 1] xs ready

    // ================= Layer 0: n-slice 32, m = 128, K = 256 (r10) =========
    f32x4 acc0[2][8];   // [at][bt] = 64 VGPRs
    #pragma unroll
    for (int at = 0; at < 2; ++at)
        #pragma unroll
        for (int bt = 0; bt < 8; ++bt)
            acc0[at][bt] = (f32x4){0.f, 0.f, 0.f, 0.f};

    #pragma unroll
    for (int ks = 0; ks < 8; ++ks) {
        bf16x8 na0 = a0, na1 = a1;
        if (ks < 7) {
            na0 = *(const bf16x8*)(w0r + (ks + 1) * 32);
            na1 = *(const bf16x8*)(w0r + 16 * DIN + (ks + 1) * 32);
        }
        __builtin_amdgcn_s_setprio(1);
        #pragma unroll
        for (int bt = 0; bt < 8; ++bt) {
            bf16x8 bx = *(const bf16x8*)(xs + ((bt * 8 + ks) * 64 + lane) * 8);
            acc0[0][bt] = MFMA16(a0, bx, acc0[0][bt]);
            acc0[1][bt] = MFMA16(a1, bx, acc0[1][bt]);
        }
        __builtin_amdgcn_s_setprio(0);
        a0 = na0; a1 = na1;
    }

    // prefetch W1 ks=0 (rides through barrier + epilogue)
    bf16x8 q0 = *(const bf16x8*)(w1r);

    __syncthreads();                                   // [barrier 2] xs reads done

    // ---- epilogue: bias+relu+cvt -> h0 in 32-format ------------------------
    // value: n(=k) = w*32 + at*16 + 4*l4 + r, m = bt*16 + l15
    // granule g = (bt>>1)*32 + (w*2 + at)
    // elem = ((bt&1)*16 + l15 + 32*(l4>>1))*8 + 4*(l4&1)  (+r)
    #pragma unroll
    for (int at = 0; at < 2; ++at) {
        const int nb = w * 32 + at * 16 + 4 * l4;
        const f32x4 b4 = *(const f32x4*)(b0 + c * NH0 + nb);
        const int ebase = (l15 + 32 * (l4 >> 1)) * 8 + 4 * (l4 & 1);
        #pragma unroll
        for (int bt = 0; bt < 8; ++bt) {
            const int g = (bt >> 1) * 32 + w * 2 + at;
            bf16x4 pk;
            #pragma unroll
            for (int r = 0; r < 4; ++r) {
                float v = acc0[at][bt][r] + b4[r];
                v = v > 0.f ? v : 0.f;
                pk[r] = (__bf16)v;
            }
            *(bf16x4*)(&h0s[g * 512 + ebase + (bt & 1) * 128]) = pk;
        }
    }
    __syncthreads();                                   // [barrier 3] h0 complete

    // ================= Layer 1: o-slice 32, m-half 64, K = 512 =============
    // 32x32x16 MFMA; h0 granule for (ks, bt2): g = (mh*2+bt2)*32 + ks
    f32x16 acc1[2];   // [bt2] = 32 VGPRs
    #pragma unroll
    for (int bt2 = 0; bt2 < 2; ++bt2)
        #pragma unroll
        for (int r = 0; r < 16; ++r)
            acc1[bt2][r] = 0.f;

    bf16x8 a = q0;
    #pragma unroll
    for (int ks = 0; ks < 32; ++ks) {     // K = 512, 16 per step
        bf16x8 na = a;
        if (ks < 31) na = *(const bf16x8*)(w1r + (ks + 1) * 16);
        __builtin_amdgcn_s_setprio(1);
        #pragma unroll
        for (int bt2 = 0; bt2 < 2; ++bt2) {
            bf16x8 bh = *(const bf16x8*)(h0s + (((mh * 2 + bt2) * 32 + ks) * 64 + lane) * 8);
            acc1[bt2] = MFMA32(a, bh, acc1[bt2]);
        }
        __builtin_amdgcn_s_setprio(0);
        a = na;
    }

    // ================= Layer 2 =============================================
    // acc1[bt2]: o = ns*32 + 8*q + 4*l5 + r (reg = q*4+r), m = (mh*2+bt2)*32 + l31
    float part[2] = {0.f, 0.f};
    #pragma unroll
    for (int q = 0; q < 4; ++q) {
        const int ob = ns * 32 + 8 * q + 4 * l5;
        const f32x4 b1v = *(const f32x4*)(b1 + c * NH1 + ob);
        const f32x4 w2v = *(const f32x4*)(W2 + c * NH1 + ob);
        #pragma unroll
        for (int bt2 = 0; bt2 < 2; ++bt2) {
            #pragma unroll
            for (int r = 0; r < 4; ++r) {
                float v = acc1[bt2][q * 4 + r] + b1v[r];
                v = v > 0.f ? v : 0.f;
                part[bt2] += v * w2v[r];
            }
        }
    }
    #pragma unroll
    for (int bt2 = 0; bt2 < 2; ++bt2)
        part[bt2] += __shfl_xor(part[bt2], 32, 64);   // fold l5 o-subsets
    if (l5 == 0) {
        #pragma unroll
        for (int bt2 = 0; bt2 < 2; ++bt2)
            red[w][bt2 * 32 + l31] = part[bt2];       // m-local within half
    }
    __syncthreads();                                   // [barrier 4]

    if (tid < BTM) {
        const int mh2 = tid >> 6, ml = tid & 63;      // m = mh2*64 + ml
        float s = 0.f;
        #pragma unroll
        for (int n2 = 0; n2 < 8; ++n2) s += red[n2 * 2 + mh2][ml];
        s += b2[c];
        out[(size_t)(row0 + tid) * CNUM + c] = s;
    }
}

// ---------------------------------------------------------------------------
// Fallback (fp32 loads, no workspace) in case ws_size < WS_NEED. BT=64 geom.
// ---------------------------------------------------------------------------
__device__ __forceinline__ bf16x8 ld_cvt8(const float* __restrict__ p) {
    f32x8 v = *(const f32x8*)p;
    bf16x8 r;
    #pragma unroll
    for (int i = 0; i < 8; ++i) r[i] = (__bf16)v[i];
    return r;
}

#define P0 (NH0 + 8)

__global__ __launch_bounds__(NTHREADS, 4)
void confounder_fused(const float* __restrict__ x,
                      const float* __restrict__ W0,
                      const float* __restrict__ b0,
                      const float* __restrict__ W1,
                      const float* __restrict__ b1,
                      const float* __restrict__ W2,
                      const float* __restrict__ b2,
                      float* __restrict__ out) {
    __shared__ __align__(16) __bf16 h0s[BT * P0];
    __shared__ float red[8][BT];

    const int c    = blockIdx.x & 7;
    const int mb   = blockIdx.x >> 3;
    const int row0 = mb * BT;
    const int tid  = threadIdx.x;
    const int w    = tid >> 6;
    const int lane = tid & 63;
    const int l15  = lane & 15;
    const int l4   = lane >> 4;

    f32x4 acc0[4][4];
    #pragma unroll
    for (int mt = 0; mt < 4; ++mt)
        #pragma unroll
        for (int nt = 0; nt < 4; ++nt)
            acc0[mt][nt] = (f32x4){0.f, 0.f, 0.f, 0.f};

    const float* xb  = x  + (size_t)(row0 + l15) * DIN + 8 * l4;
    const float* w0b = W0 + ((size_t)c * NH0 + w * 64 + l15) * DIN + 8 * l4;

    #pragma unroll
    for (int ks = 0; ks < DIN / 32; ++ks) {
        bf16x8 a[4];
        #pragma unroll
        for (int mt = 0; mt < 4; ++mt)
            a[mt] = ld_cvt8(xb + mt * 16 * DIN + ks * 32);
        #pragma unroll
        for (int nt = 0; nt < 4; ++nt) {
            bf16x8 bf = ld_cvt8(w0b + nt * 16 * DIN + ks * 32);
            #pragma unroll
            for (int mt = 0; mt < 4; ++mt)
                acc0[mt][nt] = __builtin_amdgcn_mfma_f32_16x16x32_bf16(a[mt], bf, acc0[mt][nt], 0, 0, 0);
        }
    }
    #pragma unroll
    for (int nt = 0; nt < 4; ++nt) {
        const int n    = (w * 4 + nt) * 16 + l15;
        const float bv = b0[c * NH0 + n];
        #pragma unroll
        for (int mt = 0; mt < 4; ++mt)
            #pragma unroll
            for (int r = 0; r < 4; ++r) {
                float v = acc0[mt][nt][r] + bv;
                v = v > 0.f ? v : 0.f;
                h0s[(mt * 16 + l4 * 4 + r) * P0 + n] = (__bf16)v;
            }
    }
    __syncthreads();

    f32x4 acc1[2][4];
    #pragma unroll
    for (int ot = 0; ot < 2; ++ot)
        #pragma unroll
        for (int nt = 0; nt < 4; ++nt)
            acc1[ot][nt] = (f32x4){0.f, 0.f, 0.f, 0.f};

    const float* w1b = W1 + ((size_t)c * NH1 + w * 32 + l15) * NH0 + 8 * l4;

    #pragma unroll
    for (int ks = 0; ks < NH0 / 32; ++ks) {
        bf16x8 a[2];
        #pragma unroll
        for (int ot = 0; ot < 2; ++ot)
            a[ot] = ld_cvt8(w1b + ot * 16 * NH0 + ks * 32);
        #pragma unroll
        for (int nt = 0; nt < 4; ++nt) {
            bf16x8 bf = *(const bf16x8*)(&h0s[(nt * 16 + l15) * P0 + ks * 32 + 8 * l4]);
            #pragma unroll
            for (int ot = 0; ot < 2; ++ot)
                acc1[ot][nt] = __builtin_amdgcn_mfma_f32_16x16x32_bf16(a[ot], bf, acc1[ot][nt], 0, 0, 0);
        }
    }

    float part[4] = {0.f, 0.f, 0.f, 0.f};
    #pragma unroll
    for (int ot = 0; ot < 2; ++ot)
        #pragma unroll
        for (int r = 0; r < 4; ++r) {
            const int o     = (2 * w + ot) * 16 + l4 * 4 + r;
            const float b1v = b1[c * NH1 + o];
            const float w2v = W2[c * NH1 + o];
            #pragma unroll
            for (int nt = 0; nt < 4; ++nt) {
                float v = acc1[ot][nt][r] + b1v;
                v = v > 0.f ? v : 0.f;
                part[nt] += v * w2v;
            }
        }
    #pragma unroll
    for (int nt = 0; nt < 4; ++nt) {
        part[nt] += __shfl_xor(part[nt], 16, 64);
        part[nt] += __shfl_xor(part[nt], 32, 64);
    }
    if (l4 == 0) {
        #pragma unroll
        for (int nt = 0; nt < 4; ++nt)
            red[w][nt * 16 + l15] = part[nt];
    }
    __syncthreads();

    if (tid < BT) {
        float s = 0.f;
        #pragma unroll
        for (int ww = 0; ww < 8; ++ww) s += red[ww][tid];
        s += b2[c];
        out[(size_t)(row0 + tid) * CNUM + c] = s;
    }
}

extern "C" void kernel_launch(void* const* d_in, const int* in_sizes, int n_in,
                              void* d_out, int out_size, void* d_ws, size_t ws_size,
                              hipStream_t stream) {
    const float* x  = (const float*)d_in[0];
    const float* W0 = (const float*)d_in[1];
    const float* b0 = (const float*)d_in[2];
    const float* W1 = (const float*)d_in[3];
    const float* b1 = (const float*)d_in[4];
    const float* W2 = (const float*)d_in[5];
    const float* b2 = (const float*)d_in[6];
    float* out = (float*)d_out;

    if (ws_size >= WS_NEED) {
        __bf16* ws = (__bf16*)d_ws;
        cvt_bf16<<<dim3((X_ELEMS + W0_ELEMS + W1_ELEMS) / 8 / 256), dim3(256), 0, stream>>>(x, W0, W1, ws);
        confounder_main<<<dim3((BATCH / BTM) * CNUM), dim3(NTMAIN), 0, stream>>>(ws, b0, b1, W2, b2, out);
    } else {
        confounder_fused<<<dim3((BATCH / BT) * CNUM), dim3(NTHREADS), 0, stream>>>(x, W0, b0, W1, b1, W2, b2, out);
    }
}

// Round 15
// 160.764 us; speedup vs baseline: 1.1670x; 1.1670x over previous
//
#include <hip/hip_runtime.h>

// Problem constants (from reference)
#define BATCH 16384
#define CNUM  8
#define DIN   256
#define NH0   512
#define NH1   256

#define BT       64            // batch rows per block (fallback kernel)
#define BTM      128           // batch rows per block (main kernel)
#define NTMAIN   1024          // 16 waves
#define NTHREADS 512           // fallback

#define X_ELEMS  (BATCH * DIN)        // 4194304
#define W0_ELEMS (CNUM * NH0 * DIN)   // 1048576
#define W1_ELEMS (CNUM * NH1 * NH0)   // 1048576
#define WS_NEED  ((size_t)(X_ELEMS + W0_ELEMS + W1_ELEMS) * 2)  // 12.6 MB bf16

typedef __bf16 bf16x8 __attribute__((ext_vector_type(8)));
typedef __bf16 bf16x4 __attribute__((ext_vector_type(4)));
typedef float  f32x4  __attribute__((ext_vector_type(4)));
typedef float  f32x8  __attribute__((ext_vector_type(8)));

#define MFMA16(a, b, c) __builtin_amdgcn_mfma_f32_16x16x32_bf16((a), (b), (c), 0, 0, 0)

// ---------------------------------------------------------------------------
// Prep: fp32 -> bf16 for x, W0, W1 into ws.  786432 chunks x 8 elems.
// ---------------------------------------------------------------------------
__global__ __launch_bounds__(256)
void cvt_bf16(const float* __restrict__ x, const float* __restrict__ W0,
              const float* __restrict__ W1, __bf16* __restrict__ ws) {
    const int i = blockIdx.x * 256 + threadIdx.x;   // chunk of 8 elems
    const float* src;
    __bf16* dst;
    int off;
    if (i < X_ELEMS / 8)                 { src = x;  dst = ws;                        off = i * 8; }
    else if (i < (X_ELEMS + W0_ELEMS)/8) { src = W0; dst = ws + X_ELEMS;             off = (i - X_ELEMS/8) * 8; }
    else                                 { src = W1; dst = ws + X_ELEMS + W0_ELEMS;  off = (i - (X_ELEMS + W0_ELEMS)/8) * 8; }
    f32x8 v = *(const f32x8*)(src + off);
    bf16x8 r;
    #pragma unroll
    for (int j = 0; j < 8; ++j) r[j] = (__bf16)v[j];
    *(bf16x8*)(dst + off) = r;
}

// ---------------------------------------------------------------------------
// Main fused kernel: BT=128, 16 waves, 4 barriers TOTAL per block.
// grid = (BATCH/BTM)*CNUM = 1024; c = blockIdx&7 (XCD round-robin; per-XCD
// L2 holds its c's 512 KB of weights -> W is L2-resident after first touch).
//
// == r10 EXACT (94.4 us, best of 15 rounds) ==
// The round-11..14 decomposition established this as a sharp local optimum:
//  - tile: BT=64 half speed, BT=256 exceeds LDS with this dataflow.
//  - partition: ANY m-split of L0 or L1 (16x16 or 32x32, 1 or 2 A-streams)
//    costs 22-29% -- per-k-step ILP (fat 8-16 MFMA clusters covering the
//    serialized A-load chain) is worth more than halving LDS-read volume.
//  - prefetch: compiler pins VGPR at 64 and re-sinks loads regardless of
//    source-level rings/fences (distance-2/4, sched_barrier, DMA+vmcnt).
//
// LDS: h0s = 128 granules x 1 KB (frag-major: granule = 16 m-rows x 32 k;
// lane l's 16 B = row l&15, k-slot l>>4 -> every ds_read_b128 is
// lane-contiguous, conflict-free). h0 granule g = bt*16 + (n>>5).
// xs (x tile, 64 granules, p = mt*8 + kc) aliases granules 0..63 in L0.
// ---------------------------------------------------------------------------
__global__ __launch_bounds__(NTMAIN, 4)
void confounder_main(const __bf16* __restrict__ ws,
                     const float* __restrict__ b0,
                     const float* __restrict__ b1,
                     const float* __restrict__ W2,
                     const float* __restrict__ b2,
                     float* __restrict__ out) {
    __shared__ __align__(16) __bf16 h0s[BTM * NH0];  // 131072 B
    __shared__ float red[16][BTM];                   // 8192 B
    __bf16* xs = h0s;                                // granules 0..63 alias

    const __bf16* xbf = ws;
    const __bf16* w0b = ws + X_ELEMS;
    const __bf16* w1b = ws + X_ELEMS + W0_ELEMS;

    const int c    = blockIdx.x & 7;
    const int mb   = blockIdx.x >> 3;
    const int row0 = mb * BTM;

    const int tid  = threadIdx.x;
    const int w    = tid >> 6;    // wave 0..15
    const int lane = tid & 63;
    const int l15  = lane & 15;
    const int l4   = lane >> 4;   // 0..3

    // ---- stage x tile (128 m x 256 k) into granules 0..63, frag-major -----
    // granule p = mt*8 + kc; lane: row mt*16+l15, cols kc*32 + 8*l4 .. +7
    #pragma unroll
    for (int q = 0; q < 4; ++q) {
        const int p  = w * 4 + q;             // 0..63
        const int mt = p >> 3, kc = p & 7;
        bf16x8 v = *(const bf16x8*)(xbf + (size_t)(row0 + mt * 16 + l15) * DIN + kc * 32 + 8 * l4);
        *(bf16x8*)(xs + (p * 64 + lane) * 8) = v;
    }

    // W0 rows: wave w covers n = w*32 + at*16 + l15 (at 0..1)
    const __bf16* w0r = w0b + ((size_t)c * NH0 + w * 32 + l15) * DIN + 8 * l4;
    // W1 rows: wave w covers o = w*16 + l15
    const __bf16* w1r = w1b + ((size_t)c * NH1 + w * 16 + l15) * NH0 + 8 * l4;

    // prefetch L0 ks=0 fragments across the barrier
    bf16x8 a0 = *(const bf16x8*)(w0r);
    bf16x8 a1 = *(const bf16x8*)(w0r + 16 * DIN);
    __syncthreads();                                   // [barrier 1] xs ready

    // ================= Layer 0: n-slice 32, m = 128, K = 256 ===============
    f32x4 acc0[2][8];   // [at][bt] = 64 VGPRs
    #pragma unroll
    for (int at = 0; at < 2; ++at)
        #pragma unroll
        for (int bt = 0; bt < 8; ++bt)
            acc0[at][bt] = (f32x4){0.f, 0.f, 0.f, 0.f};

    #pragma unroll
    for (int ks = 0; ks < 8; ++ks) {
        bf16x8 na0 = a0, na1 = a1;
        if (ks < 7) {
            na0 = *(const bf16x8*)(w0r + (ks + 1) * 32);
            na1 = *(const bf16x8*)(w0r + 16 * DIN + (ks + 1) * 32);
        }
        __builtin_amdgcn_s_setprio(1);
        #pragma unroll
        for (int bt = 0; bt < 8; ++bt) {
            bf16x8 bx = *(const bf16x8*)(xs + ((bt * 8 + ks) * 64 + lane) * 8);
            acc0[0][bt] = MFMA16(a0, bx, acc0[0][bt]);
            acc0[1][bt] = MFMA16(a1, bx, acc0[1][bt]);
        }
        __builtin_amdgcn_s_setprio(0);
        a0 = na0; a1 = na1;
    }

    // prefetch W1 ks=0 (rides through barrier + epilogue)
    bf16x8 q0 = *(const bf16x8*)(w1r);

    __syncthreads();                                   // [barrier 2] xs reads done

    // ---- epilogue: bias+relu+cvt -> h0 granule g = bt*16 + w --------------
    // n = w*32 + at*16 + 4*l4 + r, m = bt*16 + l15
    #pragma unroll
    for (int at = 0; at < 2; ++at) {
        const int nb = w * 32 + at * 16 + 4 * l4;
        const f32x4 b4 = *(const f32x4*)(b0 + c * NH0 + nb);
        const int sub = (at * 2 + (l4 >> 1)) * 128 + l15 * 8 + 4 * (l4 & 1);
        #pragma unroll
        for (int bt = 0; bt < 8; ++bt) {
            const int g = bt * 16 + w;
            bf16x4 pk;
            #pragma unroll
            for (int r = 0; r < 4; ++r) {
                float v = acc0[at][bt][r] + b4[r];
                v = v > 0.f ? v : 0.f;
                pk[r] = (__bf16)v;
            }
            *(bf16x4*)(&h0s[g * 512 + sub]) = pk;
        }
    }
    __syncthreads();                                   // [barrier 3] h0 complete

    // ================= Layer 1: o-slice 16, m = 128, K = 512 ===============
    // h0 granule for (ks, bt): g = bt*16 + ks
    f32x4 acc1[8];   // [bt] = 32 VGPRs
    #pragma unroll
    for (int bt = 0; bt < 8; ++bt)
        acc1[bt] = (f32x4){0.f, 0.f, 0.f, 0.f};

    bf16x8 a = q0;
    #pragma unroll
    for (int ks = 0; ks < 16; ++ks) {
        bf16x8 na = a;
        if (ks < 15) na = *(const bf16x8*)(w1r + (ks + 1) * 32);
        __builtin_amdgcn_s_setprio(1);
        #pragma unroll
        for (int bt = 0; bt < 8; ++bt) {
            bf16x8 bh = *(const bf16x8*)(&h0s[((bt * 16 + ks) * 64 + lane) * 8]);
            acc1[bt] = MFMA16(a, bh, acc1[bt]);
        }
        __builtin_amdgcn_s_setprio(0);
        a = na;
    }

    // ================= Layer 2 =============================================
    // acc1[bt]: o = w*16 + 4*l4 + r, m = bt*16 + l15
    float part[8] = {0.f, 0.f, 0.f, 0.f, 0.f, 0.f, 0.f, 0.f};
    {
        const int ob = w * 16 + 4 * l4;
        const f32x4 b1v = *(const f32x4*)(b1 + c * NH1 + ob);
        const f32x4 w2v = *(const f32x4*)(W2 + c * NH1 + ob);
        #pragma unroll
        for (int r = 0; r < 4; ++r) {
            #pragma unroll
            for (int bt = 0; bt < 8; ++bt) {
                float v = acc1[bt][r] + b1v[r];
                v = v > 0.f ? v : 0.f;
                part[bt] += v * w2v[r];
            }
        }
    }
    #pragma unroll
    for (int bt = 0; bt < 8; ++bt) {
        part[bt] += __shfl_xor(part[bt], 16, 64);
        part[bt] += __shfl_xor(part[bt], 32, 64);
    }
    if (l4 == 0) {
        #pragma unroll
        for (int bt = 0; bt < 8; ++bt)
            red[w][bt * 16 + l15] = part[bt];
    }
    __syncthreads();                                   // [barrier 4]

    if (tid < BTM) {
        float s = 0.f;
        #pragma unroll
        for (int ww = 0; ww < 16; ++ww) s += red[ww][tid];
        s += b2[c];
        out[(size_t)(row0 + tid) * CNUM + c] = s;
    }
}

// ---------------------------------------------------------------------------
// Fallback (fp32 loads, no workspace) in case ws_size < WS_NEED. BT=64 geom.
// ---------------------------------------------------------------------------
__device__ __forceinline__ bf16x8 ld_cvt8(const float* __restrict__ p) {
    f32x8 v = *(const f32x8*)p;
    bf16x8 r;
    #pragma unroll
    for (int i = 0; i < 8; ++i) r[i] = (__bf16)v[i];
    return r;
}

#define P0 (NH0 + 8)

__global__ __launch_bounds__(NTHREADS, 4)
void confounder_fused(const float* __restrict__ x,
                      const float* __restrict__ W0,
                      const float* __restrict__ b0,
                      const float* __restrict__ W1,
                      const float* __restrict__ b1,
                      const float* __restrict__ W2,
                      const float* __restrict__ b2,
                      float* __restrict__ out) {
    __shared__ __align__(16) __bf16 h0s[BT * P0];
    __shared__ float red[8][BT];

    const int c    = blockIdx.x & 7;
    const int mb   = blockIdx.x >> 3;
    const int row0 = mb * BT;
    const int tid  = threadIdx.x;
    const int w    = tid >> 6;
    const int lane = tid & 63;
    const int l15  = lane & 15;
    const int l4   = lane >> 4;

    f32x4 acc0[4][4];
    #pragma unroll
    for (int mt = 0; mt < 4; ++mt)
        #pragma unroll
        for (int nt = 0; nt < 4; ++nt)
            acc0[mt][nt] = (f32x4){0.f, 0.f, 0.f, 0.f};

    const float* xb  = x  + (size_t)(row0 + l15) * DIN + 8 * l4;
    const float* w0b = W0 + ((size_t)c * NH0 + w * 64 + l15) * DIN + 8 * l4;

    #pragma unroll
    for (int ks = 0; ks < DIN / 32; ++ks) {
        bf16x8 a[4];
        #pragma unroll
        for (int mt = 0; mt < 4; ++mt)
            a[mt] = ld_cvt8(xb + mt * 16 * DIN + ks * 32);
        #pragma unroll
        for (int nt = 0; nt < 4; ++nt) {
            bf16x8 bf = ld_cvt8(w0b + nt * 16 * DIN + ks * 32);
            #pragma unroll
            for (int mt = 0; mt < 4; ++mt)
                acc0[mt][nt] = __builtin_amdgcn_mfma_f32_16x16x32_bf16(a[mt], bf, acc0[mt][nt], 0, 0, 0);
        }
    }
    #pragma unroll
    for (int nt = 0; nt < 4; ++nt) {
        const int n    = (w * 4 + nt) * 16 + l15;
        const float bv = b0[c * NH0 + n];
        #pragma unroll
        for (int mt = 0; mt < 4; ++mt)
            #pragma unroll
            for (int r = 0; r < 4; ++r) {
                float v = acc0[mt][nt][r] + bv;
                v = v > 0.f ? v : 0.f;
                h0s[(mt * 16 + l4 * 4 + r) * P0 + n] = (__bf16)v;
            }
    }
    __syncthreads();

    f32x4 acc1[2][4];
    #pragma unroll
    for (int ot = 0; ot < 2; ++ot)
        #pragma unroll
        for (int nt = 0; nt < 4; ++nt)
            acc1[ot][nt] = (f32x4){0.f, 0.f, 0.f, 0.f};

    const float* w1b = W1 + ((size_t)c * NH1 + w * 32 + l15) * NH0 + 8 * l4;

    #pragma unroll
    for (int ks = 0; ks < NH0 / 32; ++ks) {
        bf16x8 a[2];
        #pragma unroll
        for (int ot = 0; ot < 2; ++ot)
            a[ot] = ld_cvt8(w1b + ot * 16 * NH0 + ks * 32);
        #pragma unroll
        for (int nt = 0; nt < 4; ++nt) {
            bf16x8 bf = *(const bf16x8*)(&h0s[(nt * 16 + l15) * P0 + ks * 32 + 8 * l4]);
            #pragma unroll
            for (int ot = 0; ot < 2; ++ot)
                acc1[ot][nt] = __builtin_amdgcn_mfma_f32_16x16x32_bf16(a[ot], bf, acc1[ot][nt], 0, 0, 0);
        }
    }

    float part[4] = {0.f, 0.f, 0.f, 0.f};
    #pragma unroll
    for (int ot = 0; ot < 2; ++ot)
        #pragma unroll
        for (int r = 0; r < 4; ++r) {
            const int o     = (2 * w + ot) * 16 + l4 * 4 + r;
            const float b1v = b1[c * NH1 + o];
            const float w2v = W2[c * NH1 + o];
            #pragma unroll
            for (int nt = 0; nt < 4; ++nt) {
                float v = acc1[ot][nt][r] + b1v;
                v = v > 0.f ? v : 0.f;
                part[nt] += v * w2v;
            }
        }
    #pragma unroll
    for (int nt = 0; nt < 4; ++nt) {
        part[nt] += __shfl_xor(part[nt], 16, 64);
        part[nt] += __shfl_xor(part[nt], 32, 64);
    }
    if (l4 == 0) {
        #pragma unroll
        for (int nt = 0; nt < 4; ++nt)
            red[w][nt * 16 + l15] = part[nt];
    }
    __syncthreads();

    if (tid < BT) {
        float s = 0.f;
        #pragma unroll
        for (int ww = 0; ww < 8; ++ww) s += red[ww][tid];
        s += b2[c];
        out[(size_t)(row0 + tid) * CNUM + c] = s;
    }
}

extern "C" void kernel_launch(void* const* d_in, const int* in_sizes, int n_in,
                              void* d_out, int out_size, void* d_ws, size_t ws_size,
                              hipStream_t stream) {
    const float* x  = (const float*)d_in[0];
    const float* W0 = (const float*)d_in[1];
    const float* b0 = (const float*)d_in[2];
    const float* W1 = (const float*)d_in[3];
    const float* b1 = (const float*)d_in[4];
    const float* W2 = (const float*)d_in[5];
    const float* b2 = (const float*)d_in[6];
    float* out = (float*)d_out;

    if (ws_size >= WS_NEED) {
        __bf16* ws = (__bf16*)d_ws;
        cvt_bf16<<<dim3((X_ELEMS + W0_ELEMS + W1_ELEMS) / 8 / 256), dim3(256), 0, stream>>>(x, W0, W1, ws);
        confounder_main<<<dim3((BATCH / BTM) * CNUM), dim3(NTMAIN), 0, stream>>>(ws, b0, b1, W2, b2, out);
    } else {
        confounder_fused<<<dim3((BATCH / BT) * CNUM), dim3(NTHREADS), 0, stream>>>(x, W0, b0, W1, b1, W2, b2, out);
    }
}

// Round 16
// 159.257 us; speedup vs baseline: 1.1781x; 1.0095x over previous
//
#include <hip/hip_runtime.h>

// Problem constants (from reference)
#define BATCH 16384
#define CNUM  8
#define DIN   256
#define NH0   512
#define NH1   256

#define BT       64            // batch rows per block (fallback kernel)
#define BTM      128           // batch rows per block (main kernel)
#define NTMAIN   1024          // 16 waves
#define NTHREADS 512           // fallback

#define X_ELEMS  (BATCH * DIN)        // 4194304
#define W0_ELEMS (CNUM * NH0 * DIN)   // 1048576
#define W1_ELEMS (CNUM * NH1 * NH0)   // 1048576
#define WS_NEED  ((size_t)(X_ELEMS + W0_ELEMS + W1_ELEMS) * 2)  // 12.6 MB bf16

typedef __bf16 bf16x8 __attribute__((ext_vector_type(8)));
typedef __bf16 bf16x4 __attribute__((ext_vector_type(4)));
typedef float  f32x4  __attribute__((ext_vector_type(4)));
typedef float  f32x8  __attribute__((ext_vector_type(8)));

#define MFMA16(a, b, c) __builtin_amdgcn_mfma_f32_16x16x32_bf16((a), (b), (c), 0, 0, 0)

// ---------------------------------------------------------------------------
// Prep: fp32 -> bf16 for x, W0, W1 into ws.  786432 chunks x 8 elems.
// ---------------------------------------------------------------------------
__global__ __launch_bounds__(256)
void cvt_bf16(const float* __restrict__ x, const float* __restrict__ W0,
              const float* __restrict__ W1, __bf16* __restrict__ ws) {
    const int i = blockIdx.x * 256 + threadIdx.x;   // chunk of 8 elems
    const float* src;
    __bf16* dst;
    int off;
    if (i < X_ELEMS / 8)                 { src = x;  dst = ws;                        off = i * 8; }
    else if (i < (X_ELEMS + W0_ELEMS)/8) { src = W0; dst = ws + X_ELEMS;             off = (i - X_ELEMS/8) * 8; }
    else                                 { src = W1; dst = ws + X_ELEMS + W0_ELEMS;  off = (i - (X_ELEMS + W0_ELEMS)/8) * 8; }
    f32x8 v = *(const f32x8*)(src + off);
    bf16x8 r;
    #pragma unroll
    for (int j = 0; j < 8; ++j) r[j] = (__bf16)v[j];
    *(bf16x8*)(dst + off) = r;
}

// ---------------------------------------------------------------------------
// Main fused kernel: BT=128, 16 waves, 4 barriers/block.
// grid = (BATCH/BTM)*CNUM = 1024; c = blockIdx&7 (XCD round-robin).
//
// r10 (94.4 us) with ONE change: L1 runs on 8 FAT waves instead of 16 thin.
//   L0 (r10 EXACT): wave w owns n-slice 32 (at 0..1), m = 128. 2 global
//     A-streams, 8 ds_read + 16 MFMA(16x16x32) per k-step.
//   L1 (NEW): waves 0..7 each own o-slice 32 (ot 0..1) x FULL m=128.
//     Per k-step: 2 A-streams + 8 ds_read + 16 MFMA -- the same fat-cluster
//     shape that makes L0 fast. Waves 8..15 skip to the reduce barrier.
//     Total L1 LDS reads halve (2048 -> 1024/block); per-wave ILP doubles;
//     active TLP halves. Tests the r12/r14 mechanism (both m-split variants
//     that THINNED the per-step cluster lost 29% despite halving LDS reads).
//
// LDS: h0s = 128 granules x 1 KB (frag-major: granule = 16 m-rows x 32 k;
// lane l's 16 B = row l&15, k-slot l>>4 -> every ds_read_b128 is
// lane-contiguous, conflict-free). h0 granule g = bt*16 + (n>>5).
// xs (x tile, 64 granules, p = mt*8 + kc) aliases granules 0..63 in L0.
// ---------------------------------------------------------------------------
__global__ __launch_bounds__(NTMAIN, 4)
void confounder_main(const __bf16* __restrict__ ws,
                     const float* __restrict__ b0,
                     const float* __restrict__ b1,
                     const float* __restrict__ W2,
                     const float* __restrict__ b2,
                     float* __restrict__ out) {
    __shared__ __align__(16) __bf16 h0s[BTM * NH0];  // 131072 B
    __shared__ float red[8][BTM];                    // 4096 B
    __bf16* xs = h0s;                                // granules 0..63 alias

    const __bf16* xbf = ws;
    const __bf16* w0b = ws + X_ELEMS;
    const __bf16* w1b = ws + X_ELEMS + W0_ELEMS;

    const int c    = blockIdx.x & 7;
    const int mb   = blockIdx.x >> 3;
    const int row0 = mb * BTM;

    const int tid  = threadIdx.x;
    const int w    = tid >> 6;    // wave 0..15
    const int lane = tid & 63;
    const int l15  = lane & 15;
    const int l4   = lane >> 4;   // 0..3

    // ---- stage x tile (128 m x 256 k) into granules 0..63, frag-major -----
    // granule p = mt*8 + kc; lane: row mt*16+l15, cols kc*32 + 8*l4 .. +7
    #pragma unroll
    for (int q = 0; q < 4; ++q) {
        const int p  = w * 4 + q;             // 0..63
        const int mt = p >> 3, kc = p & 7;
        bf16x8 v = *(const bf16x8*)(xbf + (size_t)(row0 + mt * 16 + l15) * DIN + kc * 32 + 8 * l4);
        *(bf16x8*)(xs + (p * 64 + lane) * 8) = v;
    }

    // W0 rows: wave w covers n = w*32 + at*16 + l15 (at 0..1)
    const __bf16* w0r = w0b + ((size_t)c * NH0 + w * 32 + l15) * DIN + 8 * l4;
    // W1 rows (L1, 8 fat waves): o = (w&7)*32 + ot*16 + l15 (ot 0..1)
    const __bf16* w1r = w1b + ((size_t)c * NH1 + (w & 7) * 32 + l15) * NH0 + 8 * l4;

    // prefetch L0 ks=0 fragments across the barrier
    bf16x8 a0 = *(const bf16x8*)(w0r);
    bf16x8 a1 = *(const bf16x8*)(w0r + 16 * DIN);
    __syncthreads();                                   // [barrier 1] xs ready

    // ================= Layer 0: n-slice 32, m = 128, K = 256 ===============
    f32x4 acc0[2][8];   // [at][bt] = 64 accumulation regs
    #pragma unroll
    for (int at = 0; at < 2; ++at)
        #pragma unroll
        for (int bt = 0; bt < 8; ++bt)
            acc0[at][bt] = (f32x4){0.f, 0.f, 0.f, 0.f};

    #pragma unroll
    for (int ks = 0; ks < 8; ++ks) {
        bf16x8 na0 = a0, na1 = a1;
        if (ks < 7) {
            na0 = *(const bf16x8*)(w0r + (ks + 1) * 32);
            na1 = *(const bf16x8*)(w0r + 16 * DIN + (ks + 1) * 32);
        }
        __builtin_amdgcn_s_setprio(1);
        #pragma unroll
        for (int bt = 0; bt < 8; ++bt) {
            bf16x8 bx = *(const bf16x8*)(xs + ((bt * 8 + ks) * 64 + lane) * 8);
            acc0[0][bt] = MFMA16(a0, bx, acc0[0][bt]);
            acc0[1][bt] = MFMA16(a1, bx, acc0[1][bt]);
        }
        __builtin_amdgcn_s_setprio(0);
        a0 = na0; a1 = na1;
    }

    // prefetch W1 ks=0, both streams (ride through barrier + epilogue);
    // waves 8..15 load harmless duplicates (w&7 keeps the address in range)
    bf16x8 q0 = *(const bf16x8*)(w1r);
    bf16x8 q1 = *(const bf16x8*)(w1r + 16 * NH0);

    __syncthreads();                                   // [barrier 2] xs reads done

    // ---- epilogue: bias+relu+cvt -> h0 granule g = bt*16 + w --------------
    // n = w*32 + at*16 + 4*l4 + r, m = bt*16 + l15
    #pragma unroll
    for (int at = 0; at < 2; ++at) {
        const int nb = w * 32 + at * 16 + 4 * l4;
        const f32x4 b4 = *(const f32x4*)(b0 + c * NH0 + nb);
        const int sub = (at * 2 + (l4 >> 1)) * 128 + l15 * 8 + 4 * (l4 & 1);
        #pragma unroll
        for (int bt = 0; bt < 8; ++bt) {
            const int g = bt * 16 + w;
            bf16x4 pk;
            #pragma unroll
            for (int r = 0; r < 4; ++r) {
                float v = acc0[at][bt][r] + b4[r];
                v = v > 0.f ? v : 0.f;
                pk[r] = (__bf16)v;
            }
            *(bf16x4*)(&h0s[g * 512 + sub]) = pk;
        }
    }
    __syncthreads();                                   // [barrier 3] h0 complete

    // ================= Layer 1: 8 fat waves, o-slice 32, m = 128, K = 512 ==
    // h0 granule for (ks, bt): g = bt*16 + ks
    if (w < 8) {
        f32x4 acc1[2][8];   // [ot][bt] = 64 accumulation regs
        #pragma unroll
        for (int ot = 0; ot < 2; ++ot)
            #pragma unroll
            for (int bt = 0; bt < 8; ++bt)
                acc1[ot][bt] = (f32x4){0.f, 0.f, 0.f, 0.f};

        bf16x8 b0f = q0, b1f = q1;
        #pragma unroll
        for (int ks = 0; ks < 16; ++ks) {
            bf16x8 n0 = b0f, n1 = b1f;
            if (ks < 15) {
                n0 = *(const bf16x8*)(w1r + (ks + 1) * 32);
                n1 = *(const bf16x8*)(w1r + 16 * NH0 + (ks + 1) * 32);
            }
            __builtin_amdgcn_s_setprio(1);
            #pragma unroll
            for (int bt = 0; bt < 8; ++bt) {
                bf16x8 bh = *(const bf16x8*)(&h0s[((bt * 16 + ks) * 64 + lane) * 8]);
                acc1[0][bt] = MFMA16(b0f, bh, acc1[0][bt]);
                acc1[1][bt] = MFMA16(b1f, bh, acc1[1][bt]);
            }
            __builtin_amdgcn_s_setprio(0);
            b0f = n0; b1f = n1;
        }

        // ---- Layer 2 partial: o = w*32 + ot*16 + 4*l4 + r, m = bt*16 + l15
        float part[8] = {0.f, 0.f, 0.f, 0.f, 0.f, 0.f, 0.f, 0.f};
        #pragma unroll
        for (int ot = 0; ot < 2; ++ot) {
            const int ob = w * 32 + ot * 16 + 4 * l4;
            const f32x4 b1v = *(const f32x4*)(b1 + c * NH1 + ob);
            const f32x4 w2v = *(const f32x4*)(W2 + c * NH1 + ob);
            #pragma unroll
            for (int r = 0; r < 4; ++r) {
                #pragma unroll
                for (int bt = 0; bt < 8; ++bt) {
                    float v = acc1[ot][bt][r] + b1v[r];
                    v = v > 0.f ? v : 0.f;
                    part[bt] += v * w2v[r];
                }
            }
        }
        #pragma unroll
        for (int bt = 0; bt < 8; ++bt) {
            part[bt] += __shfl_xor(part[bt], 16, 64);
            part[bt] += __shfl_xor(part[bt], 32, 64);
        }
        if (l4 == 0) {
            #pragma unroll
            for (int bt = 0; bt < 8; ++bt)
                red[w][bt * 16 + l15] = part[bt];
        }
    }
    __syncthreads();                                   // [barrier 4]

    if (tid < BTM) {
        float s = 0.f;
        #pragma unroll
        for (int ww = 0; ww < 8; ++ww) s += red[ww][tid];
        s += b2[c];
        out[(size_t)(row0 + tid) * CNUM + c] = s;
    }
}

// ---------------------------------------------------------------------------
// Fallback (fp32 loads, no workspace) in case ws_size < WS_NEED. BT=64 geom.
// ---------------------------------------------------------------------------
__device__ __forceinline__ bf16x8 ld_cvt8(const float* __restrict__ p) {
    f32x8 v = *(const f32x8*)p;
    bf16x8 r;
    #pragma unroll
    for (int i = 0; i < 8; ++i) r[i] = (__bf16)v[i];
    return r;
}

#define P0 (NH0 + 8)

__global__ __launch_bounds__(NTHREADS, 4)
void confounder_fused(const float* __restrict__ x,
                      const float* __restrict__ W0,
                      const float* __restrict__ b0,
                      const float* __restrict__ W1,
                      const float* __restrict__ b1,
                      const float* __restrict__ W2,
                      const float* __restrict__ b2,
                      float* __restrict__ out) {
    __shared__ __align__(16) __bf16 h0s[BT * P0];
    __shared__ float red[8][BT];

    const int c    = blockIdx.x & 7;
    const int mb   = blockIdx.x >> 3;
    const int row0 = mb * BT;
    const int tid  = threadIdx.x;
    const int w    = tid >> 6;
    const int lane = tid & 63;
    const int l15  = lane & 15;
    const int l4   = lane >> 4;

    f32x4 acc0[4][4];
    #pragma unroll
    for (int mt = 0; mt < 4; ++mt)
        #pragma unroll
        for (int nt = 0; nt < 4; ++nt)
            acc0[mt][nt] = (f32x4){0.f, 0.f, 0.f, 0.f};

    const float* xb  = x  + (size_t)(row0 + l15) * DIN + 8 * l4;
    const float* w0b = W0 + ((size_t)c * NH0 + w * 64 + l15) * DIN + 8 * l4;

    #pragma unroll
    for (int ks = 0; ks < DIN / 32; ++ks) {
        bf16x8 a[4];
        #pragma unroll
        for (int mt = 0; mt < 4; ++mt)
            a[mt] = ld_cvt8(xb + mt * 16 * DIN + ks * 32);
        #pragma unroll
        for (int nt = 0; nt < 4; ++nt) {
            bf16x8 bf = ld_cvt8(w0b + nt * 16 * DIN + ks * 32);
            #pragma unroll
            for (int mt = 0; mt < 4; ++mt)
                acc0[mt][nt] = __builtin_amdgcn_mfma_f32_16x16x32_bf16(a[mt], bf, acc0[mt][nt], 0, 0, 0);
        }
    }
    #pragma unroll
    for (int nt = 0; nt < 4; ++nt) {
        const int n    = (w * 4 + nt) * 16 + l15;
        const float bv = b0[c * NH0 + n];
        #pragma unroll
        for (int mt = 0; mt < 4; ++mt)
            #pragma unroll
            for (int r = 0; r < 4; ++r) {
                float v = acc0[mt][nt][r] + bv;
                v = v > 0.f ? v : 0.f;
                h0s[(mt * 16 + l4 * 4 + r) * P0 + n] = (__bf16)v;
            }
    }
    __syncthreads();

    f32x4 acc1[2][4];
    #pragma unroll
    for (int ot = 0; ot < 2; ++ot)
        #pragma unroll
        for (int nt = 0; nt < 4; ++nt)
            acc1[ot][nt] = (f32x4){0.f, 0.f, 0.f, 0.f};

    const float* w1b = W1 + ((size_t)c * NH1 + w * 32 + l15) * NH0 + 8 * l4;

    #pragma unroll
    for (int ks = 0; ks < NH0 / 32; ++ks) {
        bf16x8 a[2];
        #pragma unroll
        for (int ot = 0; ot < 2; ++ot)
            a[ot] = ld_cvt8(w1b + ot * 16 * NH0 + ks * 32);
        #pragma unroll
        for (int nt = 0; nt < 4; ++nt) {
            bf16x8 bf = *(const bf16x8*)(&h0s[(nt * 16 + l15) * P0 + ks * 32 + 8 * l4]);
            #pragma unroll
            for (int ot = 0; ot < 2; ++ot)
                acc1[ot][nt] = __builtin_amdgcn_mfma_f32_16x16x32_bf16(a[ot], bf, acc1[ot][nt], 0, 0, 0);
        }
    }

    float part[4] = {0.f, 0.f, 0.f, 0.f};
    #pragma unroll
    for (int ot = 0; ot < 2; ++ot)
        #pragma unroll
        for (int r = 0; r < 4; ++r) {
            const int o     = (2 * w + ot) * 16 + l4 * 4 + r;
            const float b1v = b1[c * NH1 + o];
            const float w2v = W2[c * NH1 + o];
            #pragma unroll
            for (int nt = 0; nt < 4; ++nt) {
                float v = acc1[ot][nt][r] + b1v;
                v = v > 0.f ? v : 0.f;
                part[nt] += v * w2v;
            }
        }
    #pragma unroll
    for (int nt = 0; nt < 4; ++nt) {
        part[nt] += __shfl_xor(part[nt], 16, 64);
        part[nt] += __shfl_xor(part[nt], 32, 64);
    }
    if (l4 == 0) {
        #pragma unroll
        for (int nt = 0; nt < 4; ++nt)
            red[w][nt * 16 + l15] = part[nt];
    }
    __syncthreads();

    if (tid < BT) {
        float s = 0.f;
        #pragma unroll
        for (int ww = 0; ww < 8; ++ww) s += red[ww][tid];
        s += b2[c];
        out[(size_t)(row0 + tid) * CNUM + c] = s;
    }
}

extern "C" void kernel_launch(void* const* d_in, const int* in_sizes, int n_in,
                              void* d_out, int out_size, void* d_ws, size_t ws_size,
                              hipStream_t stream) {
    const float* x  = (const float*)d_in[0];
    const float* W0 = (const float*)d_in[1];
    const float* b0 = (const float*)d_in[2];
    const float* W1 = (const float*)d_in[3];
    const float* b1 = (const float*)d_in[4];
    const float* W2 = (const float*)d_in[5];
    const float* b2 = (const float*)d_in[6];
    float* out = (float*)d_out;

    if (ws_size >= WS_NEED) {
        __bf16* ws = (__bf16*)d_ws;
        cvt_bf16<<<dim3((X_ELEMS + W0_ELEMS + W1_ELEMS) / 8 / 256), dim3(256), 0, stream>>>(x, W0, W1, ws);
        confounder_main<<<dim3((BATCH / BTM) * CNUM), dim3(NTMAIN), 0, stream>>>(ws, b0, b1, W2, b2, out);
    } else {
        confounder_fused<<<dim3((BATCH / BT) * CNUM), dim3(NTHREADS), 0, stream>>>(x, W0, b0, W1, b1, W2, b2, out);
    }
}